// Round 15
// baseline (236.941 us; speedup 1.0000x reference)
//
#include <hip/hip_runtime.h>
#include <stdint.h>

#define NUM_HEADS 12
#define DH 64
#define SEQ 2048
#define BATCH 2
#define DM 768
#define NQK 1536  // Q cols [0,768) | K cols [768,1536)
#define LOG2E 1.44269504088896340736f

typedef short short8 __attribute__((ext_vector_type(8)));
typedef short short4_t __attribute__((ext_vector_type(4)));
typedef float f32x4 __attribute__((ext_vector_type(4)));
typedef unsigned long long u64;

__device__ __forceinline__ short bf16_rne(float f) {
    union { float f; uint32_t u; } v; v.f = f;
    return (short)((v.u + 0x7FFFu + ((v.u >> 16) & 1u)) >> 16);
}

// ---------------- Kernel 0: prep (wt | mpack), branch on blockIdx ----------------
__global__ __launch_bounds__(256) void prep_kernel(const float* __restrict__ Wq,
                                                   const float* __restrict__ Wk,
                                                   const int* __restrict__ mask,
                                                   short* __restrict__ Wt,
                                                   u64* __restrict__ Mb) {
    __shared__ float tile[32][33];
    const int bid = blockIdx.x;
    const int t = threadIdx.x;
    if (bid < 1152) {
        int n0 = (bid % 48) * 32;
        int k0 = (bid / 48) * 32;
        int tx = t & 31;
        int ty = t >> 5;
        const float* src = (n0 < DM) ? Wq : Wk;
        int nn0 = (n0 < DM) ? n0 : n0 - DM;
#pragma unroll
        for (int j = 0; j < 4; ++j) {
            int k = ty + 8 * j;
            tile[k][tx] = src[(size_t)(k0 + k) * DM + nn0 + tx];
        }
        __syncthreads();
#pragma unroll
        for (int j = 0; j < 4; ++j) {
            int n = ty + 8 * j;
            Wt[(size_t)(n0 + n) * DM + k0 + tx] = bf16_rne(tile[tx][n]);
        }
    } else {
        int wid = (bid - 1152) * 4 + (t >> 6);
        int lane = t & 63;
        size_t base = (size_t)wid * 8;
#pragma unroll
        for (int i = 0; i < 8; ++i) {
            size_t w = base + i;
            int v = mask[w * 64 + lane];
            u64 bal = __ballot(v != 0);
            if (lane == 0) Mb[w] = bal;
        }
    }
}

// ---------------- Kernel 1: projection GEMM (128x128, BK=64; A staged from f32 x) ----------------
__global__ __launch_bounds__(256) void proj_kernel(const float* __restrict__ x,
                                                   const short* __restrict__ Wt,
                                                   const float* __restrict__ bq,
                                                   const float* __restrict__ bk,
                                                   short* __restrict__ QK) {
    __shared__ short As[128 * 72];
    __shared__ short Bs[128 * 72];
    const int m0 = blockIdx.x * 128;
    const int n0 = blockIdx.y * 128;
    const int t = threadIdx.x;
    const int lane = t & 63;
    const int w = t >> 6;
    const int wr = w >> 1, wc = w & 1;
    const int lr = lane & 15;
    const int lk = lane >> 4;

    f32x4 acc[4][4] = {};

    for (int k0 = 0; k0 < DM; k0 += 64) {
#pragma unroll
        for (int j = 0; j < 4; ++j) {
            int idx = t + 256 * j;
            int row = idx >> 3;
            int ch = idx & 7;
            const float* xp = &x[(size_t)(m0 + row) * DM + k0 + ch * 8];
            f32x4 v0 = *(const f32x4*)xp;
            f32x4 v1 = *(const f32x4*)(xp + 4);
            short8 s;
#pragma unroll
            for (int e = 0; e < 4; ++e) { s[e] = bf16_rne(v0[e]); s[e + 4] = bf16_rne(v1[e]); }
            *(short8*)&As[row * 72 + ch * 8] = s;
            *(short8*)&Bs[row * 72 + ch * 8] =
                *(const short8*)&Wt[(size_t)(n0 + row) * DM + k0 + ch * 8];
        }
        __syncthreads();
#pragma unroll
        for (int kk = 0; kk < 2; ++kk) {
            short8 a[4], bfr[4];
#pragma unroll
            for (int m = 0; m < 4; ++m)
                a[m] = *(short8*)&As[(wr * 64 + m * 16 + lr) * 72 + kk * 32 + lk * 8];
#pragma unroll
            for (int n = 0; n < 4; ++n)
                bfr[n] = *(short8*)&Bs[(wc * 64 + n * 16 + lr) * 72 + kk * 32 + lk * 8];
#pragma unroll
            for (int m = 0; m < 4; ++m)
#pragma unroll
                for (int n = 0; n < 4; ++n)
                    acc[m][n] = __builtin_amdgcn_mfma_f32_16x16x32_bf16(a[m], bfr[n], acc[m][n], 0, 0, 0);
        }
        __syncthreads();
    }

    const int orow = m0 + wr * 64;
    const int ocol = n0 + wc * 64;
#pragma unroll
    for (int m = 0; m < 4; ++m) {
#pragma unroll
        for (int n = 0; n < 4; ++n) {
            int col = ocol + n * 16 + lr;
            float bias = (col < DM) ? bq[col] : bk[col - DM];
            float scale = (col < DM) ? 0.125f * LOG2E : 1.0f;
#pragma unroll
            for (int r = 0; r < 4; ++r) {
                int row = orow + m * 16 + lk * 4 + r;
                QK[(size_t)row * NQK + col] = bf16_rne((acc[m][n][r] + bias) * scale);
            }
        }
    }
}

// ---------------- Kernel 2: attn — pass A keys-split direct-read (no LDS/barriers),
//                  pass B = R11 staged + Pb store-transpose; XCD clustering ----------------
__global__ __launch_bounds__(256) void attn_kernel(const short* __restrict__ QK,
                                                   const u64* __restrict__ Mb,
                                                   float* __restrict__ out) {
    __shared__ short Ks[2][64 * 72];   // 18.4 KB
    __shared__ float Pb[64 * 132];     // 33.8 KB
    __shared__ float red[4][4][16];    // 1 KB: [wave][qf][row] pass-A partial denominators
    const int bid = blockIdx.x;
    const int xcd = bid & 7;
    const int jj = bid >> 3;
    const int bh = xcd * 3 + (jj >> 5);
    const int qblk = jj & 31;
    const int b = bh / NUM_HEADS;
    const int h = bh % NUM_HEADS;
    const int t = threadIdx.x;
    const int lane = t & 63;
    const int w = t >> 6;
    const int lr = lane & 15;
    const int lk = lane >> 4;
    const int qb = qblk * 64;
    const int wq = qb + w * 16;

    // Q fragments for all 4 q-groups (pass A needs all; pass B uses aq[w])
    short8 aq[4][2];
#pragma unroll
    for (int qf = 0; qf < 4; ++qf)
#pragma unroll
        for (int ks = 0; ks < 2; ++ks)
            aq[qf][ks] = *(const short8*)&QK[(size_t)(b * SEQ + qb + qf * 16 + lr) * NQK +
                                             h * DH + ks * 32 + lk * 8];

    // ---- pass A: keys-split (wave w owns keys [w*512,(w+1)*512)), direct global reads ----
    size_t mrowA[4];
#pragma unroll
    for (int qf = 0; qf < 4; ++qf)
        mrowA[qf] = (size_t)b * SEQ * 32 + (size_t)(qb + qf * 16 + lr) * 32;
    const short* kbase = QK + (size_t)(b * SEQ) * NQK + DM + h * DH + lk * 8;
    const int kw0 = w * 512;

    float lsum[4] = {0.f, 0.f, 0.f, 0.f};
#pragma unroll
    for (int it = 0; it < 8; ++it) {
        const int kt = kw0 + it * 64;
        u64 mq[4];
#pragma unroll
        for (int qf = 0; qf < 4; ++qf) mq[qf] = Mb[mrowA[qf] + (kt >> 6)] >> (lk * 4);
#pragma unroll
        for (int kg = 0; kg < 4; ++kg) {
            const short* kr = kbase + (size_t)(kt + kg * 16 + lr) * NQK;
            short8 k0 = *(const short8*)kr;
            short8 k1 = *(const short8*)(kr + 32);
#pragma unroll
            for (int qf = 0; qf < 4; ++qf) {
                f32x4 a = {0.f, 0.f, 0.f, 0.f};
                a = __builtin_amdgcn_mfma_f32_16x16x32_bf16(k0, aq[qf][0], a, 0, 0, 0);
                a = __builtin_amdgcn_mfma_f32_16x16x32_bf16(k1, aq[qf][1], a, 0, 0, 0);
#pragma unroll
                for (int r = 0; r < 4; ++r) {
                    float e = __builtin_amdgcn_exp2f(a[r]);
                    lsum[qf] += ((mq[qf] >> (kg * 16 + r)) & 1ull) ? e : 0.f;
                }
            }
        }
    }
    // reduce within wave (over the lk key-split), publish per-wave partials
#pragma unroll
    for (int qf = 0; qf < 4; ++qf) {
        float l = lsum[qf];
        l += __shfl_xor(l, 16, 64);
        l += __shfl_xor(l, 32, 64);
        if (lane < 16) red[w][qf][lr] = l;
    }

    // ---- pass B: R11 structure (staged Ks, Pb store-transpose) ----
    const size_t mrow0 = (size_t)b * SEQ * 32;
    const int srow = t >> 3, sch = t & 7;

#define ATT_STAGE(KT)                                                                             \
    {                                                                                             \
        _Pragma("unroll") for (int tb = 0; tb < 2; ++tb) {                                        \
            *(short8*)&Ks[tb][srow * 72 + sch * 8] =                                              \
                *(const short8*)&QK[(size_t)(b * SEQ + (KT) + tb * 64 + srow) * NQK + DM +        \
                                    h * DH + sch * 8];                                            \
            *(short8*)&Ks[tb][(srow + 32) * 72 + sch * 8] =                                       \
                *(const short8*)&QK[(size_t)(b * SEQ + (KT) + tb * 64 + srow + 32) * NQK + DM +   \
                                    h * DH + sch * 8];                                            \
        }                                                                                         \
    }

    ATT_STAGE(0)
    __syncthreads();   // red visible + Ks[g=0] ready
    float inv[4];
#pragma unroll
    for (int r = 0; r < 4; ++r)
        inv[r] = 1.0f / (red[0][w][lk * 4 + r] + red[1][w][lk * 4 + r] +
                         red[2][w][lk * 4 + r] + red[3][w][lk * 4 + r]);

    const size_t obase0 = ((size_t)((b * NUM_HEADS + h) * SEQ) + qb) * SEQ;
    for (int kt = 0; kt < SEQ; kt += 128) {
#pragma unroll
        for (int tb = 0; tb < 2; ++tb) {
            f32x4 sc[4];
#pragma unroll
            for (int nf = 0; nf < 4; ++nf) {
                short8 k0 = *(short8*)&Ks[tb][(nf * 16 + lr) * 72 + lk * 8];
                short8 k1 = *(short8*)&Ks[tb][(nf * 16 + lr) * 72 + 32 + lk * 8];
                f32x4 a = {0.f, 0.f, 0.f, 0.f};
                a = __builtin_amdgcn_mfma_f32_16x16x32_bf16(aq[w][0], k0, a, 0, 0, 0);
                a = __builtin_amdgcn_mfma_f32_16x16x32_bf16(aq[w][1], k1, a, 0, 0, 0);
                sc[nf] = a;
            }
#pragma unroll
            for (int r = 0; r < 4; ++r) {
                int q = wq + lk * 4 + r;
                int qloc = w * 16 + lk * 4 + r;
                u64 mbs = Mb[mrow0 + (size_t)q * 32 + ((kt >> 6) + tb)] >> lr;
#pragma unroll
                for (int nf = 0; nf < 4; ++nf) {
                    float p = __builtin_amdgcn_exp2f(sc[nf][r]) * inv[r];
                    Pb[qloc * 132 + tb * 64 + nf * 16 + lr] =
                        ((mbs >> (nf * 16)) & 1ull) ? p : 0.f;
                }
            }
        }
        __syncthreads();   // Pb ready, Ks consumed
#pragma unroll
        for (int g = 0; g < 8; ++g) {
            int row = g * 8 + (t >> 5);
            int col = (t & 31) * 4;
            *(f32x4*)&out[obase0 + (size_t)row * SEQ + kt + col] = *(f32x4*)&Pb[row * 132 + col];
        }
        if (kt + 128 < SEQ) ATT_STAGE(kt + 128)
        __syncthreads();   // Ks ready, Pb consumed
    }
#undef ATT_STAGE
}

extern "C" void kernel_launch(void* const* d_in, const int* in_sizes, int n_in,
                              void* d_out, int out_size, void* d_ws, size_t ws_size,
                              hipStream_t stream) {
    (void)in_sizes; (void)n_in; (void)out_size; (void)ws_size;
    const float* x = (const float*)d_in[0];
    const int* mask = (const int*)d_in[1];
    const float* Wq = (const float*)d_in[2];
    const float* bq = (const float*)d_in[3];
    const float* Wk = (const float*)d_in[4];
    const float* bk = (const float*)d_in[5];
    float* out = (float*)d_out;

    short* Wt = (short*)d_ws;                           // 1536*768 bf16
    short* QK = Wt + (size_t)NQK * DM;                  // 4096*1536 bf16
    u64* Mb = (u64*)(QK + (size_t)BATCH * SEQ * NQK);   // 131072 u64

    prep_kernel<<<dim3(1152 + 4096), 256, 0, stream>>>(Wq, Wk, mask, Wt, Mb);
    proj_kernel<<<dim3(BATCH * SEQ / 128, NQK / 128), 256, 0, stream>>>(x, Wt, bq, bk, QK);
    attn_kernel<<<dim3(768), 256, 0, stream>>>(QK, Mb, out);
}

// Round 16
// 169.024 us; speedup vs baseline: 1.4018x; 1.4018x over previous
//
#include <hip/hip_runtime.h>
#include <stdint.h>

#define NUM_HEADS 12
#define DH 64
#define SEQ 2048
#define BATCH 2
#define DM 768
#define NQK 1536  // Q cols [0,768) | K cols [768,1536)
#define LOG2E 1.44269504088896340736f

typedef short short8 __attribute__((ext_vector_type(8)));
typedef short short4_t __attribute__((ext_vector_type(4)));
typedef float f32x4 __attribute__((ext_vector_type(4)));
typedef unsigned long long u64;

__device__ __forceinline__ short bf16_rne(float f) {
    union { float f; uint32_t u; } v; v.f = f;
    return (short)((v.u + 0x7FFFu + ((v.u >> 16) & 1u)) >> 16);
}

// ---------------- Kernel 0: prep (wt | mpack), branch on blockIdx ----------------
__global__ __launch_bounds__(256) void prep_kernel(const float* __restrict__ Wq,
                                                   const float* __restrict__ Wk,
                                                   const int* __restrict__ mask,
                                                   short* __restrict__ Wt,
                                                   u64* __restrict__ Mb) {
    __shared__ float tile[32][33];
    const int bid = blockIdx.x;
    const int t = threadIdx.x;
    if (bid < 1152) {
        int n0 = (bid % 48) * 32;
        int k0 = (bid / 48) * 32;
        int tx = t & 31;
        int ty = t >> 5;
        const float* src = (n0 < DM) ? Wq : Wk;
        int nn0 = (n0 < DM) ? n0 : n0 - DM;
#pragma unroll
        for (int j = 0; j < 4; ++j) {
            int k = ty + 8 * j;
            tile[k][tx] = src[(size_t)(k0 + k) * DM + nn0 + tx];
        }
        __syncthreads();
#pragma unroll
        for (int j = 0; j < 4; ++j) {
            int n = ty + 8 * j;
            Wt[(size_t)(n0 + n) * DM + k0 + tx] = bf16_rne(tile[tx][n]);
        }
    } else {
        int wid = (bid - 1152) * 4 + (t >> 6);
        int lane = t & 63;
        size_t base = (size_t)wid * 8;
#pragma unroll
        for (int i = 0; i < 8; ++i) {
            size_t w = base + i;
            int v = mask[w * 64 + lane];
            u64 bal = __ballot(v != 0);
            if (lane == 0) Mb[w] = bal;
        }
    }
}

// ---------------- Kernel 1: projection GEMM (128x128, BK=64; A staged from f32 x) ----------------
__global__ __launch_bounds__(256) void proj_kernel(const float* __restrict__ x,
                                                   const short* __restrict__ Wt,
                                                   const float* __restrict__ bq,
                                                   const float* __restrict__ bk,
                                                   short* __restrict__ QK) {
    __shared__ short As[128 * 72];
    __shared__ short Bs[128 * 72];
    const int m0 = blockIdx.x * 128;
    const int n0 = blockIdx.y * 128;
    const int t = threadIdx.x;
    const int lane = t & 63;
    const int w = t >> 6;
    const int wr = w >> 1, wc = w & 1;
    const int lr = lane & 15;
    const int lk = lane >> 4;

    f32x4 acc[4][4] = {};

    for (int k0 = 0; k0 < DM; k0 += 64) {
#pragma unroll
        for (int j = 0; j < 4; ++j) {
            int idx = t + 256 * j;
            int row = idx >> 3;
            int ch = idx & 7;
            const float* xp = &x[(size_t)(m0 + row) * DM + k0 + ch * 8];
            f32x4 v0 = *(const f32x4*)xp;
            f32x4 v1 = *(const f32x4*)(xp + 4);
            short8 s;
#pragma unroll
            for (int e = 0; e < 4; ++e) { s[e] = bf16_rne(v0[e]); s[e + 4] = bf16_rne(v1[e]); }
            *(short8*)&As[row * 72 + ch * 8] = s;
            *(short8*)&Bs[row * 72 + ch * 8] =
                *(const short8*)&Wt[(size_t)(n0 + row) * DM + k0 + ch * 8];
        }
        __syncthreads();
#pragma unroll
        for (int kk = 0; kk < 2; ++kk) {
            short8 a[4], bfr[4];
#pragma unroll
            for (int m = 0; m < 4; ++m)
                a[m] = *(short8*)&As[(wr * 64 + m * 16 + lr) * 72 + kk * 32 + lk * 8];
#pragma unroll
            for (int n = 0; n < 4; ++n)
                bfr[n] = *(short8*)&Bs[(wc * 64 + n * 16 + lr) * 72 + kk * 32 + lk * 8];
#pragma unroll
            for (int m = 0; m < 4; ++m)
#pragma unroll
                for (int n = 0; n < 4; ++n)
                    acc[m][n] = __builtin_amdgcn_mfma_f32_16x16x32_bf16(a[m], bfr[n], acc[m][n], 0, 0, 0);
        }
        __syncthreads();
    }

    const int orow = m0 + wr * 64;
    const int ocol = n0 + wc * 64;
#pragma unroll
    for (int m = 0; m < 4; ++m) {
#pragma unroll
        for (int n = 0; n < 4; ++n) {
            int col = ocol + n * 16 + lr;
            float bias = (col < DM) ? bq[col] : bk[col - DM];
            float scale = (col < DM) ? 0.125f * LOG2E : 1.0f;
#pragma unroll
            for (int r = 0; r < 4; ++r) {
                int row = orow + m * 16 + lk * 4 + r;
                QK[(size_t)row * NQK + col] = bf16_rne((acc[m][n][r] + bias) * scale);
            }
        }
    }
}

// ---------------- Kernel 2: attn (R11 skeleton; wave = (q-half, key-tile) split) ----------------
// Wave w: qh=w&1 -> rows qblk*64+qh*32+[0,32); tbw=w>>1 -> 64-key tile of the staged 128.
// Each K fragment ds_read once per wave-pair and reused for 2 Q-frags (half the LDS reads of R11).
__global__ __launch_bounds__(256) void attn_kernel(const short* __restrict__ QK,
                                                   const u64* __restrict__ Mb,
                                                   float* __restrict__ out) {
    __shared__ short Ks[2][64 * 72];   // 18.4 KB
    __shared__ float Pb[64 * 132];     // 33.8 KB
    __shared__ float red[4][2][16];    // 512 B: [wave][qf][row] denominator partials
    const int bid = blockIdx.x;
    const int xcd = bid & 7;
    const int jj = bid >> 3;
    const int bh = xcd * 3 + (jj >> 5);
    const int qblk = jj & 31;
    const int b = bh / NUM_HEADS;
    const int h = bh % NUM_HEADS;
    const int t = threadIdx.x;
    const int lane = t & 63;
    const int w = t >> 6;
    const int qh = w & 1;
    const int tbw = w >> 1;
    const int lr = lane & 15;
    const int lk = lane >> 4;
    const int qb = qblk * 64;
    const int rowbase = qb + qh * 32;

    // Q fragments for this wave's 32 rows (pre-scaled by 0.125*log2e in projection)
    short8 aq[2][2];
#pragma unroll
    for (int qf = 0; qf < 2; ++qf)
#pragma unroll
        for (int ks = 0; ks < 2; ++ks)
            aq[qf][ks] = *(const short8*)&QK[(size_t)(b * SEQ + rowbase + qf * 16 + lr) * NQK +
                                             h * DH + ks * 32 + lk * 8];

    float lrow[2][4] = {};
    const size_t mrow0 = (size_t)b * SEQ * 32;
    const int srow = t >> 3, sch = t & 7;

#define ATT_STAGE(KT)                                                                             \
    {                                                                                             \
        _Pragma("unroll") for (int tb = 0; tb < 2; ++tb) {                                        \
            *(short8*)&Ks[tb][srow * 72 + sch * 8] =                                              \
                *(const short8*)&QK[(size_t)(b * SEQ + (KT) + tb * 64 + srow) * NQK + DM +        \
                                    h * DH + sch * 8];                                            \
            *(short8*)&Ks[tb][(srow + 32) * 72 + sch * 8] =                                       \
                *(const short8*)&QK[(size_t)(b * SEQ + (KT) + tb * 64 + srow + 32) * NQK + DM +   \
                                    h * DH + sch * 8];                                            \
        }                                                                                         \
    }

    // ---- pass A: masked sum of exp2 (each wave: its 64-key tile x its 32 rows) ----
    for (int kt = 0; kt < SEQ; kt += 128) {
        ATT_STAGE(kt)
        __syncthreads();
#pragma unroll
        for (int qf = 0; qf < 2; ++qf) {
            f32x4 sc[4];
#pragma unroll
            for (int nf = 0; nf < 4; ++nf) {
                short8 k0 = *(short8*)&Ks[tbw][(nf * 16 + lr) * 72 + lk * 8];
                short8 k1 = *(short8*)&Ks[tbw][(nf * 16 + lr) * 72 + 32 + lk * 8];
                f32x4 a = {0.f, 0.f, 0.f, 0.f};
                a = __builtin_amdgcn_mfma_f32_16x16x32_bf16(aq[qf][0], k0, a, 0, 0, 0);
                a = __builtin_amdgcn_mfma_f32_16x16x32_bf16(aq[qf][1], k1, a, 0, 0, 0);
                sc[nf] = a;
            }
#pragma unroll
            for (int r = 0; r < 4; ++r) {
                int q = rowbase + qf * 16 + lk * 4 + r;
                u64 mbs = Mb[mrow0 + (size_t)q * 32 + (kt >> 6) + tbw] >> lr;
                float s = 0.f;
#pragma unroll
                for (int nf = 0; nf < 4; ++nf) {
                    float e = __builtin_amdgcn_exp2f(sc[nf][r]);
                    s += ((mbs >> (nf * 16)) & 1ull) ? e : 0.f;
                }
                lrow[qf][r] += s;
            }
        }
        __syncthreads();
    }

    // ---- reduce over the 16 key-lanes, publish per-wave partials ----
#pragma unroll
    for (int qf = 0; qf < 2; ++qf) {
#pragma unroll
        for (int r = 0; r < 4; ++r) {
            float l = lrow[qf][r];
            l += __shfl_xor(l, 1, 64);
            l += __shfl_xor(l, 2, 64);
            l += __shfl_xor(l, 4, 64);
            l += __shfl_xor(l, 8, 64);
            if (lr == 0) red[w][qf][lk * 4 + r] = l;
        }
    }
    __syncthreads();
    float inv[2][4];
#pragma unroll
    for (int qf = 0; qf < 2; ++qf)
#pragma unroll
        for (int r = 0; r < 4; ++r)
            inv[qf][r] = 1.0f / (red[qh][qf][lk * 4 + r] + red[qh + 2][qf][lk * 4 + r]);

    // ---- pass B: recompute -> Pb (LDS) -> 512B-segment coalesced stores ----
    const size_t obase0 = ((size_t)((b * NUM_HEADS + h) * SEQ) + qb) * SEQ;
    for (int kt = 0; kt < SEQ; kt += 128) {
        ATT_STAGE(kt)
        __syncthreads();   // Ks ready; also fences previous group's Pb reads
#pragma unroll
        for (int qf = 0; qf < 2; ++qf) {
            f32x4 sc[4];
#pragma unroll
            for (int nf = 0; nf < 4; ++nf) {
                short8 k0 = *(short8*)&Ks[tbw][(nf * 16 + lr) * 72 + lk * 8];
                short8 k1 = *(short8*)&Ks[tbw][(nf * 16 + lr) * 72 + 32 + lk * 8];
                f32x4 a = {0.f, 0.f, 0.f, 0.f};
                a = __builtin_amdgcn_mfma_f32_16x16x32_bf16(aq[qf][0], k0, a, 0, 0, 0);
                a = __builtin_amdgcn_mfma_f32_16x16x32_bf16(aq[qf][1], k1, a, 0, 0, 0);
                sc[nf] = a;
            }
#pragma unroll
            for (int r = 0; r < 4; ++r) {
                int q = rowbase + qf * 16 + lk * 4 + r;
                int qloc = qh * 32 + qf * 16 + lk * 4 + r;
                u64 mbs = Mb[mrow0 + (size_t)q * 32 + (kt >> 6) + tbw] >> lr;
#pragma unroll
                for (int nf = 0; nf < 4; ++nf) {
                    float p = __builtin_amdgcn_exp2f(sc[nf][r]) * inv[qf][r];
                    Pb[qloc * 132 + tbw * 64 + nf * 16 + lr] =
                        ((mbs >> (nf * 16)) & 1ull) ? p : 0.f;
                }
            }
        }
        __syncthreads();   // Pb ready
#pragma unroll
        for (int g = 0; g < 8; ++g) {
            int row = g * 8 + (t >> 5);
            int col = (t & 31) * 4;
            *(f32x4*)&out[obase0 + (size_t)row * SEQ + kt + col] = *(f32x4*)&Pb[row * 132 + col];
        }
    }
#undef ATT_STAGE
}

extern "C" void kernel_launch(void* const* d_in, const int* in_sizes, int n_in,
                              void* d_out, int out_size, void* d_ws, size_t ws_size,
                              hipStream_t stream) {
    (void)in_sizes; (void)n_in; (void)out_size; (void)ws_size;
    const float* x = (const float*)d_in[0];
    const int* mask = (const int*)d_in[1];
    const float* Wq = (const float*)d_in[2];
    const float* bq = (const float*)d_in[3];
    const float* Wk = (const float*)d_in[4];
    const float* bk = (const float*)d_in[5];
    float* out = (float*)d_out;

    short* Wt = (short*)d_ws;                           // 1536*768 bf16
    short* QK = Wt + (size_t)NQK * DM;                  // 4096*1536 bf16
    u64* Mb = (u64*)(QK + (size_t)BATCH * SEQ * NQK);   // 131072 u64

    prep_kernel<<<dim3(1152 + 4096), 256, 0, stream>>>(Wq, Wk, mask, Wt, Mb);
    proj_kernel<<<dim3(BATCH * SEQ / 128, NQK / 128), 256, 0, stream>>>(x, Wt, bq, bk, QK);
    attn_kernel<<<dim3(768), 256, 0, stream>>>(QK, Mb, out);
}

// Round 17
// 151.072 us; speedup vs baseline: 1.5684x; 1.1188x over previous
//
#include <hip/hip_runtime.h>
#include <stdint.h>

#define NUM_HEADS 12
#define DH 64
#define SEQ 2048
#define BATCH 2
#define DM 768
#define NQK 1536  // Q cols [0,768) | K cols [768,1536)
#define LOG2E 1.44269504088896340736f

typedef short short8 __attribute__((ext_vector_type(8)));
typedef short short4_t __attribute__((ext_vector_type(4)));
typedef float f32x4 __attribute__((ext_vector_type(4)));
typedef unsigned long long u64;

__device__ __forceinline__ short bf16_rne(float f) {
    union { float f; uint32_t u; } v; v.f = f;
    return (short)((v.u + 0x7FFFu + ((v.u >> 16) & 1u)) >> 16);
}

// async global->LDS, 16B per lane; LDS dest = wave-uniform base + lane*16 (linear)
#define GLOAD_LDS(gp, lp)                                                          \
    __builtin_amdgcn_global_load_lds(                                              \
        (const __attribute__((address_space(1))) void*)(gp),                       \
        (__attribute__((address_space(3))) void*)(lp), 16, 0, 0)

// ---------------- Kernel 0: prep (wt | xb | mpack), branch on blockIdx ----------------
__global__ __launch_bounds__(256) void prep_kernel(const float* __restrict__ Wq,
                                                   const float* __restrict__ Wk,
                                                   const float* __restrict__ x,
                                                   const int* __restrict__ mask,
                                                   short* __restrict__ Wt,
                                                   short* __restrict__ Xb,
                                                   u64* __restrict__ Mb) {
    __shared__ float tile[32][33];
    const int bid = blockIdx.x;
    const int t = threadIdx.x;
    if (bid < 1152) {
        int n0 = (bid % 48) * 32;
        int k0 = (bid / 48) * 32;
        int tx = t & 31;
        int ty = t >> 5;
        const float* src = (n0 < DM) ? Wq : Wk;
        int nn0 = (n0 < DM) ? n0 : n0 - DM;
#pragma unroll
        for (int j = 0; j < 4; ++j) {
            int k = ty + 8 * j;
            tile[k][tx] = src[(size_t)(k0 + k) * DM + nn0 + tx];
        }
        __syncthreads();
#pragma unroll
        for (int j = 0; j < 4; ++j) {
            int n = ty + 8 * j;
            Wt[(size_t)(n0 + n) * DM + k0 + tx] = bf16_rne(tile[tx][n]);
        }
    } else if (bid < 1920) {
        // ---- xb: x -> bf16 ----
        size_t base = (size_t)(bid - 1152) * 4096;
#pragma unroll
        for (int j = 0; j < 4; ++j) {
            size_t i = base + (size_t)(t + j * 256) * 4;
            f32x4 v = *(const f32x4*)(x + i);
            short4_t s;
#pragma unroll
            for (int e = 0; e < 4; ++e) s[e] = bf16_rne(v[e]);
            *(short4_t*)(Xb + i) = s;
        }
    } else {
        // ---- mpack ----
        int wid = (bid - 1920) * 4 + (t >> 6);
        int lane = t & 63;
        size_t base = (size_t)wid * 8;
#pragma unroll
        for (int i = 0; i < 8; ++i) {
            size_t w = base + i;
            int v = mask[w * 64 + lane];
            u64 bal = __ballot(v != 0);
            if (lane == 0) Mb[w] = bal;
        }
    }
}

// ---------------- Kernel 1: proj GEMM (128x128, BK=64), global_load_lds staging ----------------
// LDS linear [128][64] shorts; swizzle: 16B-chunk c' = c ^ (row&7) applied on the
// global SOURCE address (linear LDS dest) and on the fragment READ (rule #21 involution).
__global__ __launch_bounds__(256) void proj_kernel(const short* __restrict__ Xb,
                                                   const short* __restrict__ Wt,
                                                   const float* __restrict__ bq,
                                                   const float* __restrict__ bk,
                                                   short* __restrict__ QK) {
    __shared__ short As[128 * 64];  // 16 KB
    __shared__ short Bs[128 * 64];  // 16 KB
    const int m0 = blockIdx.x * 128;
    const int n0 = blockIdx.y * 128;
    const int t = threadIdx.x;
    const int lane = t & 63;
    const int w = t >> 6;
    const int wr = w >> 1, wc = w & 1;
    const int lr = lane & 15;
    const int lk = lane >> 4;
    const int crow = lane >> 3;            // row within 8-row chunk
    const int cc = (lane & 7) ^ crow;      // swizzled source 16B-chunk index
    const int xr = (lr & 7) << 4;          // read-side XOR (row&7)<<4 bytes

    f32x4 acc[4][4] = {};

    for (int k0 = 0; k0 < DM; k0 += 64) {
#pragma unroll
        for (int i = 0; i < 4; ++i) {
            int ci = w * 4 + i;            // 16 chunks of 8 rows x 1KB
            int row = ci * 8 + crow;
            GLOAD_LDS(&Xb[(size_t)(m0 + row) * DM + k0 + cc * 8], &As[ci * 512]);
            GLOAD_LDS(&Wt[(size_t)(n0 + row) * DM + k0 + cc * 8], &Bs[ci * 512]);
        }
        __syncthreads();
#pragma unroll
        for (int kk = 0; kk < 2; ++kk) {
            short8 a[4], bfr[4];
#pragma unroll
            for (int m = 0; m < 4; ++m) {
                int row = wr * 64 + m * 16 + lr;
                a[m] = *(short8*)((char*)As + row * 128 + ((kk * 64 + lk * 16) ^ xr));
            }
#pragma unroll
            for (int n = 0; n < 4; ++n) {
                int row = wc * 64 + n * 16 + lr;
                bfr[n] = *(short8*)((char*)Bs + row * 128 + ((kk * 64 + lk * 16) ^ xr));
            }
#pragma unroll
            for (int m = 0; m < 4; ++m)
#pragma unroll
                for (int n = 0; n < 4; ++n)
                    acc[m][n] = __builtin_amdgcn_mfma_f32_16x16x32_bf16(a[m], bfr[n], acc[m][n], 0, 0, 0);
        }
        __syncthreads();
    }

    const int orow = m0 + wr * 64;
    const int ocol = n0 + wc * 64;
#pragma unroll
    for (int m = 0; m < 4; ++m) {
#pragma unroll
        for (int n = 0; n < 4; ++n) {
            int col = ocol + n * 16 + lr;
            float bias = (col < DM) ? bq[col] : bk[col - DM];
            float scale = (col < DM) ? 0.125f * LOG2E : 1.0f;
#pragma unroll
            for (int r = 0; r < 4; ++r) {
                int row = orow + m * 16 + lk * 4 + r;
                QK[(size_t)row * NQK + col] = bf16_rne((acc[m][n][r] + bias) * scale);
            }
        }
    }
}

// ---------------- Kernel 2: attn (R11, frozen: LDS store-transpose + XCD clustering) ----------------
__global__ __launch_bounds__(256) void attn_kernel(const short* __restrict__ QK,
                                                   const u64* __restrict__ Mb,
                                                   float* __restrict__ out) {
    __shared__ short Ks[2][64 * 72];   // 18.4 KB
    __shared__ float Pb[64 * 132];     // 33.8 KB
    const int bid = blockIdx.x;
    const int xcd = bid & 7;
    const int jj = bid >> 3;
    const int bh = xcd * 3 + (jj >> 5);
    const int qblk = jj & 31;
    const int b = bh / NUM_HEADS;
    const int h = bh % NUM_HEADS;
    const int t = threadIdx.x;
    const int lane = t & 63;
    const int w = t >> 6;
    const int lr = lane & 15;
    const int lk = lane >> 4;
    const int wq = qblk * 64 + w * 16;

    short8 aq[2];
#pragma unroll
    for (int ks = 0; ks < 2; ++ks)
        aq[ks] = *(const short8*)&QK[(size_t)(b * SEQ + wq + lr) * NQK + h * DH + ks * 32 + lk * 8];

    float lrow[4] = {0.f, 0.f, 0.f, 0.f};
    const size_t mrow0 = (size_t)b * SEQ * 32;
    const int srow = t >> 3, sch = t & 7;

#define ATT_STAGE(KT)                                                                             \
    {                                                                                             \
        _Pragma("unroll") for (int tb = 0; tb < 2; ++tb) {                                        \
            *(short8*)&Ks[tb][srow * 72 + sch * 8] =                                              \
                *(const short8*)&QK[(size_t)(b * SEQ + (KT) + tb * 64 + srow) * NQK + DM +        \
                                    h * DH + sch * 8];                                            \
            *(short8*)&Ks[tb][(srow + 32) * 72 + sch * 8] =                                       \
                *(const short8*)&QK[(size_t)(b * SEQ + (KT) + tb * 64 + srow + 32) * NQK + DM +   \
                                    h * DH + sch * 8];                                            \
        }                                                                                         \
    }

    // ---- pass A: masked sum of exp2 ----
    for (int kt = 0; kt < SEQ; kt += 128) {
        ATT_STAGE(kt)
        __syncthreads();
#pragma unroll
        for (int tb = 0; tb < 2; ++tb) {
            f32x4 sc[4];
#pragma unroll
            for (int nf = 0; nf < 4; ++nf) {
                short8 k0 = *(short8*)&Ks[tb][(nf * 16 + lr) * 72 + lk * 8];
                short8 k1 = *(short8*)&Ks[tb][(nf * 16 + lr) * 72 + 32 + lk * 8];
                f32x4 a = {0.f, 0.f, 0.f, 0.f};
                a = __builtin_amdgcn_mfma_f32_16x16x32_bf16(aq[0], k0, a, 0, 0, 0);
                a = __builtin_amdgcn_mfma_f32_16x16x32_bf16(aq[1], k1, a, 0, 0, 0);
                sc[nf] = a;
            }
#pragma unroll
            for (int r = 0; r < 4; ++r) {
                int q = wq + lk * 4 + r;
                u64 mbs = Mb[mrow0 + (size_t)q * 32 + ((kt >> 6) + tb)] >> lr;
                float s = 0.f;
#pragma unroll
                for (int nf = 0; nf < 4; ++nf) {
                    float e = __builtin_amdgcn_exp2f(sc[nf][r]);
                    s += ((mbs >> (nf * 16)) & 1ull) ? e : 0.f;
                }
                lrow[r] += s;
            }
        }
        __syncthreads();
    }

    // ---- reduce over the 16 key-lanes ----
    float inv[4];
#pragma unroll
    for (int r = 0; r < 4; ++r) {
        float l = lrow[r];
        l += __shfl_xor(l, 1, 64);
        l += __shfl_xor(l, 2, 64);
        l += __shfl_xor(l, 4, 64);
        l += __shfl_xor(l, 8, 64);
        inv[r] = 1.0f / l;
    }

    // ---- pass B: recompute -> Pb (LDS) -> 512B-segment coalesced stores ----
    const size_t obase0 = ((size_t)((b * NUM_HEADS + h) * SEQ) + qblk * 64) * SEQ;
    for (int kt = 0; kt < SEQ; kt += 128) {
        ATT_STAGE(kt)
        __syncthreads();
#pragma unroll
        for (int tb = 0; tb < 2; ++tb) {
            f32x4 sc[4];
#pragma unroll
            for (int nf = 0; nf < 4; ++nf) {
                short8 k0 = *(short8*)&Ks[tb][(nf * 16 + lr) * 72 + lk * 8];
                short8 k1 = *(short8*)&Ks[tb][(nf * 16 + lr) * 72 + 32 + lk * 8];
                f32x4 a = {0.f, 0.f, 0.f, 0.f};
                a = __builtin_amdgcn_mfma_f32_16x16x32_bf16(aq[0], k0, a, 0, 0, 0);
                a = __builtin_amdgcn_mfma_f32_16x16x32_bf16(aq[1], k1, a, 0, 0, 0);
                sc[nf] = a;
            }
#pragma unroll
            for (int r = 0; r < 4; ++r) {
                int q = wq + lk * 4 + r;
                int qloc = w * 16 + lk * 4 + r;
                u64 mbs = Mb[mrow0 + (size_t)q * 32 + ((kt >> 6) + tb)] >> lr;
#pragma unroll
                for (int nf = 0; nf < 4; ++nf) {
                    float p = __builtin_amdgcn_exp2f(sc[nf][r]) * inv[r];
                    Pb[qloc * 132 + tb * 64 + nf * 16 + lr] =
                        ((mbs >> (nf * 16)) & 1ull) ? p : 0.f;
                }
            }
        }
        __syncthreads();
#pragma unroll
        for (int g = 0; g < 8; ++g) {
            int row = g * 8 + (t >> 5);
            int col = (t & 31) * 4;
            *(f32x4*)&out[obase0 + (size_t)row * SEQ + kt + col] = *(f32x4*)&Pb[row * 132 + col];
        }
    }
#undef ATT_STAGE
}

extern "C" void kernel_launch(void* const* d_in, const int* in_sizes, int n_in,
                              void* d_out, int out_size, void* d_ws, size_t ws_size,
                              hipStream_t stream) {
    (void)in_sizes; (void)n_in; (void)out_size; (void)ws_size;
    const float* x = (const float*)d_in[0];
    const int* mask = (const int*)d_in[1];
    const float* Wq = (const float*)d_in[2];
    const float* bq = (const float*)d_in[3];
    const float* Wk = (const float*)d_in[4];
    const float* bk = (const float*)d_in[5];
    float* out = (float*)d_out;

    short* Wt = (short*)d_ws;                           // 1536*768 bf16
    short* Xb = Wt + (size_t)NQK * DM;                  // 4096*768 bf16
    short* QK = Xb + (size_t)BATCH * SEQ * DM;          // 4096*1536 bf16
    u64* Mb = (u64*)(QK + (size_t)BATCH * SEQ * NQK);   // 131072 u64

    prep_kernel<<<dim3(6016), 256, 0, stream>>>(Wq, Wk, x, mask, Wt, Xb, Mb);
    proj_kernel<<<dim3(BATCH * SEQ / 128, NQK / 128), 256, 0, stream>>>(Xb, Wt, bq, bk, QK);
    attn_kernel<<<dim3(768), 256, 0, stream>>>(QK, Mb, out);
}

// Round 18
// 148.651 us; speedup vs baseline: 1.5939x; 1.0163x over previous
//
#include <hip/hip_runtime.h>
#include <stdint.h>

#define NUM_HEADS 12
#define DH 64
#define SEQ 2048
#define BATCH 2
#define DM 768
#define NQK 1536  // Q cols [0,768) | K cols [768,1536)
#define LOG2E 1.44269504088896340736f

typedef short short8 __attribute__((ext_vector_type(8)));
typedef short short4_t __attribute__((ext_vector_type(4)));
typedef float f32x4 __attribute__((ext_vector_type(4)));
typedef unsigned long long u64;

__device__ __forceinline__ short bf16_rne(float f) {
    union { float f; uint32_t u; } v; v.f = f;
    return (short)((v.u + 0x7FFFu + ((v.u >> 16) & 1u)) >> 16);
}

// async global->LDS, 16B per lane; LDS dest = wave-uniform base + lane*16 (linear)
#define GLOAD_LDS(gp, lp)                                                          \
    __builtin_amdgcn_global_load_lds(                                              \
        (const __attribute__((address_space(1))) void*)(gp),                       \
        (__attribute__((address_space(3))) void*)(lp), 16, 0, 0)

// ---------------- Kernel 0: prep (wt | xb | mpack), branch on blockIdx ----------------
__global__ __launch_bounds__(256) void prep_kernel(const float* __restrict__ Wq,
                                                   const float* __restrict__ Wk,
                                                   const float* __restrict__ x,
                                                   const int* __restrict__ mask,
                                                   short* __restrict__ Wt,
                                                   short* __restrict__ Xb,
                                                   u64* __restrict__ Mb) {
    __shared__ float tile[32][33];
    const int bid = blockIdx.x;
    const int t = threadIdx.x;
    if (bid < 1152) {
        int n0 = (bid % 48) * 32;
        int k0 = (bid / 48) * 32;
        int tx = t & 31;
        int ty = t >> 5;
        const float* src = (n0 < DM) ? Wq : Wk;
        int nn0 = (n0 < DM) ? n0 : n0 - DM;
#pragma unroll
        for (int j = 0; j < 4; ++j) {
            int k = ty + 8 * j;
            tile[k][tx] = src[(size_t)(k0 + k) * DM + nn0 + tx];
        }
        __syncthreads();
#pragma unroll
        for (int j = 0; j < 4; ++j) {
            int n = ty + 8 * j;
            Wt[(size_t)(n0 + n) * DM + k0 + tx] = bf16_rne(tile[tx][n]);
        }
    } else if (bid < 1920) {
        // ---- xb: x -> bf16 ----
        size_t base = (size_t)(bid - 1152) * 4096;
#pragma unroll
        for (int j = 0; j < 4; ++j) {
            size_t i = base + (size_t)(t + j * 256) * 4;
            f32x4 v = *(const f32x4*)(x + i);
            short4_t s;
#pragma unroll
            for (int e = 0; e < 4; ++e) s[e] = bf16_rne(v[e]);
            *(short4_t*)(Xb + i) = s;
        }
    } else {
        // ---- mpack ----
        int wid = (bid - 1920) * 4 + (t >> 6);
        int lane = t & 63;
        size_t base = (size_t)wid * 8;
#pragma unroll
        for (int i = 0; i < 8; ++i) {
            size_t w = base + i;
            int v = mask[w * 64 + lane];
            u64 bal = __ballot(v != 0);
            if (lane == 0) Mb[w] = bal;
        }
    }
}

// ---------------- Kernel 1: proj GEMM (128x128, BK=64), global_load_lds staging ----------------
__global__ __launch_bounds__(256) void proj_kernel(const short* __restrict__ Xb,
                                                   const short* __restrict__ Wt,
                                                   const float* __restrict__ bq,
                                                   const float* __restrict__ bk,
                                                   short* __restrict__ QK) {
    __shared__ short As[128 * 64];  // 16 KB
    __shared__ short Bs[128 * 64];  // 16 KB
    const int m0 = blockIdx.x * 128;
    const int n0 = blockIdx.y * 128;
    const int t = threadIdx.x;
    const int lane = t & 63;
    const int w = t >> 6;
    const int wr = w >> 1, wc = w & 1;
    const int lr = lane & 15;
    const int lk = lane >> 4;
    const int crow = lane >> 3;            // row within 8-row chunk
    const int cc = (lane & 7) ^ crow;      // swizzled source 16B-chunk index
    const int xr = (lr & 7) << 4;          // read-side XOR (row&7)<<4 bytes

    f32x4 acc[4][4] = {};

    for (int k0 = 0; k0 < DM; k0 += 64) {
#pragma unroll
        for (int i = 0; i < 4; ++i) {
            int ci = w * 4 + i;            // 16 chunks of 8 rows x 1KB
            int row = ci * 8 + crow;
            GLOAD_LDS(&Xb[(size_t)(m0 + row) * DM + k0 + cc * 8], &As[ci * 512]);
            GLOAD_LDS(&Wt[(size_t)(n0 + row) * DM + k0 + cc * 8], &Bs[ci * 512]);
        }
        __syncthreads();
#pragma unroll
        for (int kk = 0; kk < 2; ++kk) {
            short8 a[4], bfr[4];
#pragma unroll
            for (int m = 0; m < 4; ++m) {
                int row = wr * 64 + m * 16 + lr;
                a[m] = *(short8*)((char*)As + row * 128 + ((kk * 64 + lk * 16) ^ xr));
            }
#pragma unroll
            for (int n = 0; n < 4; ++n) {
                int row = wc * 64 + n * 16 + lr;
                bfr[n] = *(short8*)((char*)Bs + row * 128 + ((kk * 64 + lk * 16) ^ xr));
            }
#pragma unroll
            for (int m = 0; m < 4; ++m)
#pragma unroll
                for (int n = 0; n < 4; ++n)
                    acc[m][n] = __builtin_amdgcn_mfma_f32_16x16x32_bf16(a[m], bfr[n], acc[m][n], 0, 0, 0);
        }
        __syncthreads();
    }

    const int orow = m0 + wr * 64;
    const int ocol = n0 + wc * 64;
#pragma unroll
    for (int m = 0; m < 4; ++m) {
#pragma unroll
        for (int n = 0; n < 4; ++n) {
            int col = ocol + n * 16 + lr;
            float bias = (col < DM) ? bq[col] : bk[col - DM];
            float scale = (col < DM) ? 0.125f * LOG2E : 1.0f;
#pragma unroll
            for (int r = 0; r < 4; ++r) {
                int row = orow + m * 16 + lk * 4 + r;
                QK[(size_t)row * NQK + col] = bf16_rne((acc[m][n][r] + bias) * scale);
            }
        }
    }
}

// ---------------- Kernel 2: attn (R11 + global_load_lds K-staging, swizzled linear Ks) ----------------
__global__ __launch_bounds__(256) void attn_kernel(const short* __restrict__ QK,
                                                   const u64* __restrict__ Mb,
                                                   float* __restrict__ out) {
    __shared__ short Ks[2][64 * 64];   // 16 KB (linear, swizzled)
    __shared__ float Pb[64 * 132];     // 33.8 KB
    const int bid = blockIdx.x;
    const int xcd = bid & 7;
    const int jj = bid >> 3;
    const int bh = xcd * 3 + (jj >> 5);
    const int qblk = jj & 31;
    const int b = bh / NUM_HEADS;
    const int h = bh % NUM_HEADS;
    const int t = threadIdx.x;
    const int lane = t & 63;
    const int w = t >> 6;
    const int lr = lane & 15;
    const int lk = lane >> 4;
    const int wq = qblk * 64 + w * 16;
    const int crow = lane >> 3;            // row within 8-row region
    const int cc = (lane & 7) ^ crow;      // swizzled source chunk
    const int xr = (lr & 7) << 4;          // read-side XOR

    short8 aq[2];
#pragma unroll
    for (int ks = 0; ks < 2; ++ks)
        aq[ks] = *(const short8*)&QK[(size_t)(b * SEQ + wq + lr) * NQK + h * DH + ks * 32 + lk * 8];

    float lrow[4] = {0.f, 0.f, 0.f, 0.f};
    const size_t mrow0 = (size_t)b * SEQ * 32;

    // stage 128 keys: 16 regions of 8 rows x 1KB; wave w handles regions w*4..w*4+3
#define ATT_STAGE(KT)                                                                             \
    {                                                                                             \
        _Pragma("unroll") for (int i = 0; i < 4; ++i) {                                           \
            int ci = w * 4 + i;                                                                   \
            int tile = ci >> 3;                                                                   \
            int reg = ci & 7;                                                                     \
            int row = reg * 8 + crow;                                                             \
            GLOAD_LDS(&QK[(size_t)(b * SEQ + (KT) + tile * 64 + row) * NQK + DM + h * DH +        \
                          cc * 8],                                                                \
                      &Ks[tile][reg * 512]);                                                      \
        }                                                                                         \
    }

#define K_READ(TB, NF, OFS)                                                                       \
    (*(short8*)((char*)&Ks[TB][0] + ((NF) * 16 + lr) * 128 + (((OFS) + lk * 16) ^ xr)))

    // ---- pass A: masked sum of exp2 ----
    for (int kt = 0; kt < SEQ; kt += 128) {
        ATT_STAGE(kt)
        __syncthreads();
#pragma unroll
        for (int tb = 0; tb < 2; ++tb) {
            f32x4 sc[4];
#pragma unroll
            for (int nf = 0; nf < 4; ++nf) {
                short8 k0 = K_READ(tb, nf, 0);
                short8 k1 = K_READ(tb, nf, 64);
                f32x4 a = {0.f, 0.f, 0.f, 0.f};
                a = __builtin_amdgcn_mfma_f32_16x16x32_bf16(aq[0], k0, a, 0, 0, 0);
                a = __builtin_amdgcn_mfma_f32_16x16x32_bf16(aq[1], k1, a, 0, 0, 0);
                sc[nf] = a;
            }
#pragma unroll
            for (int r = 0; r < 4; ++r) {
                int q = wq + lk * 4 + r;
                u64 mbs = Mb[mrow0 + (size_t)q * 32 + ((kt >> 6) + tb)] >> lr;
                float s = 0.f;
#pragma unroll
                for (int nf = 0; nf < 4; ++nf) {
                    float e = __builtin_amdgcn_exp2f(sc[nf][r]);
                    s += ((mbs >> (nf * 16)) & 1ull) ? e : 0.f;
                }
                lrow[r] += s;
            }
        }
        __syncthreads();
    }

    // ---- reduce over the 16 key-lanes ----
    float inv[4];
#pragma unroll
    for (int r = 0; r < 4; ++r) {
        float l = lrow[r];
        l += __shfl_xor(l, 1, 64);
        l += __shfl_xor(l, 2, 64);
        l += __shfl_xor(l, 4, 64);
        l += __shfl_xor(l, 8, 64);
        inv[r] = 1.0f / l;
    }

    // ---- pass B: recompute -> Pb (LDS) -> 512B-segment coalesced stores ----
    const size_t obase0 = ((size_t)((b * NUM_HEADS + h) * SEQ) + qblk * 64) * SEQ;
    for (int kt = 0; kt < SEQ; kt += 128) {
        ATT_STAGE(kt)
        __syncthreads();
#pragma unroll
        for (int tb = 0; tb < 2; ++tb) {
            f32x4 sc[4];
#pragma unroll
            for (int nf = 0; nf < 4; ++nf) {
                short8 k0 = K_READ(tb, nf, 0);
                short8 k1 = K_READ(tb, nf, 64);
                f32x4 a = {0.f, 0.f, 0.f, 0.f};
                a = __builtin_amdgcn_mfma_f32_16x16x32_bf16(aq[0], k0, a, 0, 0, 0);
                a = __builtin_amdgcn_mfma_f32_16x16x32_bf16(aq[1], k1, a, 0, 0, 0);
                sc[nf] = a;
            }
#pragma unroll
            for (int r = 0; r < 4; ++r) {
                int q = wq + lk * 4 + r;
                int qloc = w * 16 + lk * 4 + r;
                u64 mbs = Mb[mrow0 + (size_t)q * 32 + ((kt >> 6) + tb)] >> lr;
#pragma unroll
                for (int nf = 0; nf < 4; ++nf) {
                    float p = __builtin_amdgcn_exp2f(sc[nf][r]) * inv[r];
                    Pb[qloc * 132 + tb * 64 + nf * 16 + lr] =
                        ((mbs >> (nf * 16)) & 1ull) ? p : 0.f;
                }
            }
        }
        __syncthreads();
#pragma unroll
        for (int g = 0; g < 8; ++g) {
            int row = g * 8 + (t >> 5);
            int col = (t & 31) * 4;
            *(f32x4*)&out[obase0 + (size_t)row * SEQ + kt + col] = *(f32x4*)&Pb[row * 132 + col];
        }
    }
#undef ATT_STAGE
#undef K_READ
}

extern "C" void kernel_launch(void* const* d_in, const int* in_sizes, int n_in,
                              void* d_out, int out_size, void* d_ws, size_t ws_size,
                              hipStream_t stream) {
    (void)in_sizes; (void)n_in; (void)out_size; (void)ws_size;
    const float* x = (const float*)d_in[0];
    const int* mask = (const int*)d_in[1];
    const float* Wq = (const float*)d_in[2];
    const float* bq = (const float*)d_in[3];
    const float* Wk = (const float*)d_in[4];
    const float* bk = (const float*)d_in[5];
    float* out = (float*)d_out;

    short* Wt = (short*)d_ws;                           // 1536*768 bf16
    short* Xb = Wt + (size_t)NQK * DM;                  // 4096*768 bf16
    short* QK = Xb + (size_t)BATCH * SEQ * DM;          // 4096*1536 bf16
    u64* Mb = (u64*)(QK + (size_t)BATCH * SEQ * NQK);   // 131072 u64

    prep_kernel<<<dim3(6016), 256, 0, stream>>>(Wq, Wk, x, mask, Wt, Xb, Mb);
    proj_kernel<<<dim3(BATCH * SEQ / 128, NQK / 128), 256, 0, stream>>>(Xb, Wt, bq, bk, QK);
    attn_kernel<<<dim3(768), 256, 0, stream>>>(QK, Mb, out);
}